// Round 3
// baseline (757.800 us; speedup 1.0000x reference)
//
#include <hip/hip_runtime.h>

#define D 128

// ---------------- CSR build ----------------

__global__ void k_count(const int* __restrict__ dst, int* __restrict__ deg, int E) {
  int e = blockIdx.x * blockDim.x + threadIdx.x;
  if (e < E) atomicAdd(&deg[dst[e]], 1);
}

__global__ void k_scan_intra(const int* __restrict__ deg, int* __restrict__ row_off,
                             int* __restrict__ partials, int N) {
  __shared__ int s[256];
  int t = threadIdx.x;
  int i = blockIdx.x * 256 + t;
  int v = (i < N) ? deg[i] : 0;
  s[t] = v;
  __syncthreads();
  for (int off = 1; off < 256; off <<= 1) {
    int x = 0;
    if (t >= off) x = s[t - off];
    __syncthreads();
    if (t >= off) s[t] += x;
    __syncthreads();
  }
  if (i < N) row_off[i] = s[t] - v;            // exclusive within block
  if (t == 255) partials[blockIdx.x] = s[255]; // block total
}

__global__ void k_scan_partials(int* partials, int NB) {
  __shared__ int s[256];
  __shared__ int carry;
  int t = threadIdx.x;
  if (t == 0) carry = 0;
  __syncthreads();
  for (int base = 0; base < NB; base += 256) {
    int i = base + t;
    int v = (i < NB) ? partials[i] : 0;
    s[t] = v;
    __syncthreads();
    for (int off = 1; off < 256; off <<= 1) {
      int x = 0;
      if (t >= off) x = s[t - off];
      __syncthreads();
      if (t >= off) s[t] += x;
      __syncthreads();
    }
    if (i < NB) partials[i] = carry + s[t] - v; // exclusive, with carry
    __syncthreads();
    if (t == 255) carry += s[255];
    __syncthreads();
  }
}

__global__ void k_finalize(int* __restrict__ row_off, const int* __restrict__ partials,
                           const int* __restrict__ deg, float* __restrict__ inv_deg,
                           int N, int E) {
  int i = blockIdx.x * 256 + threadIdx.x;
  if (i < N) {
    row_off[i] += partials[blockIdx.x];
    inv_deg[i] = 1.0f / fmaxf((float)deg[i], 1.0f);
  }
  if (i == N) row_off[N] = E;
}

__global__ void k_fill(const int* __restrict__ src, const int* __restrict__ dst,
                       const int* __restrict__ row_off, int* __restrict__ cursor,
                       int* __restrict__ csr, int E) {
  int e = blockIdx.x * blockDim.x + threadIdx.x;
  if (e < E) {
    int d = dst[e];
    int p = atomicAdd(&cursor[d], 1);
    csr[row_off[d] + p] = src[e];
  }
}

// ---------------- per-layer kernels ----------------

// R1-proven version: one wave per node; lane covers 2 consecutive features.
__global__ __launch_bounds__(256) void k_aggregate(const float* __restrict__ X,
    const int* __restrict__ row_off, const int* __restrict__ csr,
    const float* __restrict__ inv_deg, float* __restrict__ agg, int N) {
  int wave = (int)((blockIdx.x * blockDim.x + threadIdx.x) >> 6);
  int lane = threadIdx.x & 63;
  if (wave >= N) return;
  int start = row_off[wave], end = row_off[wave + 1];
  float2 acc = make_float2(0.f, 0.f);
  for (int base = start; base < end; base += 64) {
    int n = min(64, end - base);
    int eid = (lane < n) ? csr[base + lane] : 0;
    for (int j = 0; j < n; ++j) {
      int s = __shfl(eid, j);
      const float2 v = *(const float2*)(X + (size_t)s * D + 2 * lane);
      acc.x += v.x;
      acc.y += v.y;
    }
  }
  float inv = inv_deg[wave];
  *(float2*)(agg + (size_t)wave * D + 2 * lane) = make_float2(acc.x * inv, acc.y * inv);
}

// Fused out = ELU(agg @ Wrel + b + Xin @ Wroot). 64-row tile in LDS (64 KB).
// Thread = (column pair, row group of 16) -> 32 outputs. All lanes of a wave
// read identical LDS addresses (broadcast, conflict-free). Per-block staging
// before the barrier also keeps it safe if Xout aliases agg/Xin (fallback path).
__global__ __launch_bounds__(256) void k_layer(const float* agg,
    const float* Xin, const float* __restrict__ Wrel,
    const float* __restrict__ brel, const float* __restrict__ Wroot,
    float* Xout, int N) {
  __shared__ float sA[64 * D];
  __shared__ float sX[64 * D];
  int tid = threadIdx.x;
  int r0 = blockIdx.x * 64;
  for (int i = tid; i < 64 * 32; i += 256) { // float4 granules
    int r = i >> 5, c4 = i & 31;
    int row = r0 + r;
    float4 va = make_float4(0.f, 0.f, 0.f, 0.f), vx = va;
    if (row < N) {
      va = ((const float4*)(agg + (size_t)row * D))[c4];
      vx = ((const float4*)(Xin + (size_t)row * D))[c4];
    }
    ((float4*)(sA + r * D))[c4] = va;
    ((float4*)(sX + r * D))[c4] = vx;
  }
  __syncthreads();

  int cp = tid & 63;   // column pair: cols 2*cp, 2*cp+1
  int g = tid >> 6;    // row group 0..3
  int rb = g * 16;
  float accx[16], accy[16];
  float2 bias = ((const float2*)brel)[cp];
#pragma unroll
  for (int r = 0; r < 16; ++r) { accx[r] = bias.x; accy[r] = bias.y; }

  const float2* Wr2 = (const float2*)Wrel;
#pragma unroll 4
  for (int k4 = 0; k4 < 32; ++k4) {
    float2 w0 = Wr2[(k4 * 4 + 0) * 64 + cp];
    float2 w1 = Wr2[(k4 * 4 + 1) * 64 + cp];
    float2 w2 = Wr2[(k4 * 4 + 2) * 64 + cp];
    float2 w3 = Wr2[(k4 * 4 + 3) * 64 + cp];
#pragma unroll
    for (int r = 0; r < 16; ++r) {
      float4 a = ((const float4*)(sA + (rb + r) * D))[k4];
      accx[r] += a.x * w0.x + a.y * w1.x + a.z * w2.x + a.w * w3.x;
      accy[r] += a.x * w0.y + a.y * w1.y + a.z * w2.y + a.w * w3.y;
    }
  }
  const float2* Wo2 = (const float2*)Wroot;
#pragma unroll 4
  for (int k4 = 0; k4 < 32; ++k4) {
    float2 w0 = Wo2[(k4 * 4 + 0) * 64 + cp];
    float2 w1 = Wo2[(k4 * 4 + 1) * 64 + cp];
    float2 w2 = Wo2[(k4 * 4 + 2) * 64 + cp];
    float2 w3 = Wo2[(k4 * 4 + 3) * 64 + cp];
#pragma unroll
    for (int r = 0; r < 16; ++r) {
      float4 a = ((const float4*)(sX + (rb + r) * D))[k4];
      accx[r] += a.x * w0.x + a.y * w1.x + a.z * w2.x + a.w * w3.x;
      accy[r] += a.x * w0.y + a.y * w1.y + a.z * w2.y + a.w * w3.y;
    }
  }

  int c0 = 2 * cp;
#pragma unroll
  for (int r = 0; r < 16; ++r) {
    int row = r0 + rb + r;
    if (row < N) {
      float vx_ = accx[r], vy_ = accy[r];
      float2 o;
      o.x = vx_ > 0.f ? vx_ : expm1f(vx_);
      o.y = vy_ > 0.f ? vy_ : expm1f(vy_);
      *(float2*)(Xout + (size_t)row * D + c0) = o;
    }
  }
}

// ---------------- launch ----------------

extern "C" void kernel_launch(void* const* d_in, const int* in_sizes, int n_in,
                              void* d_out, int out_size, void* d_ws, size_t ws_size,
                              hipStream_t stream) {
  const float* X0    = (const float*)d_in[0];
  const int*   eidx  = (const int*)d_in[1];
  const float* Wrel  = (const float*)d_in[2];
  const float* brel  = (const float*)d_in[3];
  const float* Wroot = (const float*)d_in[4];
  float* out = (float*)d_out;

  const int N = in_sizes[0] / D;
  const int E = in_sizes[1] / 2;
  const int L = in_sizes[3] / D;
  const int* src = eidx;      // edge_index[0]
  const int* dst = eidx + E;  // edge_index[1]

  char* ws = (char*)d_ws;
  size_t off = 0;
  auto carve = [&](size_t bytes) -> void* {
    void* p = ws + off;
    off = (off + bytes + 255) & ~(size_t)255;
    return p;
  };
  float* xbuf0   = (float*)carve((size_t)N * D * sizeof(float));
  int*   deg     = (int*)carve((size_t)N * sizeof(int));
  int*   row_off = (int*)carve((size_t)(N + 1) * sizeof(int));
  int*   cursor  = (int*)carve((size_t)N * sizeof(int));
  int*   csr     = (int*)carve((size_t)E * sizeof(int));
  float* inv_deg = (float*)carve((size_t)N * sizeof(float));
  const int NB = (N + 255) / 256;
  int*   partials = (int*)carve((size_t)NB * sizeof(int));
  size_t need1 = off;
  float* xbuf1   = (float*)carve((size_t)N * D * sizeof(float));
  const bool two_buf = (ws_size >= off);
  (void)need1; (void)n_in; (void)out_size;

  hipMemsetAsync(deg, 0, (size_t)N * sizeof(int), stream);
  hipMemsetAsync(cursor, 0, (size_t)N * sizeof(int), stream);

  const int eb = (E + 255) / 256;
  k_count<<<eb, 256, 0, stream>>>(dst, deg, E);
  k_scan_intra<<<NB, 256, 0, stream>>>(deg, row_off, partials, N);
  k_scan_partials<<<1, 256, 0, stream>>>(partials, NB);
  k_finalize<<<NB, 256, 0, stream>>>(row_off, partials, deg, inv_deg, N, E);
  k_fill<<<eb, 256, 0, stream>>>(src, dst, row_off, cursor, csr, E);

  const int ab = (N + 3) / 4;       // k_aggregate blocks (4 waves each)
  const int lb = (N + 63) / 64;     // k_layer blocks

  if (two_buf) {
    // Alias-free rotation: agg always xbuf0; X chain X0 -> xbuf1 -> out -> xbuf1 -> out.
    const float* Xin = X0;
    for (int l = 0; l < L; ++l) {
      k_aggregate<<<ab, 256, 0, stream>>>(Xin, row_off, csr, inv_deg, xbuf0, N);
      float* Xout = (l & 1) ? out : ((l == L - 1) ? out : xbuf1);
      // l=0 -> xbuf1, l=1 -> out, l=2 -> xbuf1, l=3 -> out
      if (!(l & 1) && l != L - 1) Xout = xbuf1;
      k_layer<<<lb, 256, 0, stream>>>(xbuf0, Xin, Wrel + (size_t)l * D * D,
          brel + (size_t)l * D, Wroot + (size_t)l * D * D, Xout, N);
      Xin = Xout;
    }
  } else {
    // Fallback (R1 scheme): agg alternates out/xbuf0; k_layer per-block in-place safe.
    const float* Xin = X0;
    for (int l = 0; l < L; ++l) {
      float* a = (l & 1) ? xbuf0 : out;
      k_aggregate<<<ab, 256, 0, stream>>>(Xin, row_off, csr, inv_deg, a, N);
      float* Xout = (l == L - 1) ? out : a;
      k_layer<<<lb, 256, 0, stream>>>(a, Xin, Wrel + (size_t)l * D * D,
          brel + (size_t)l * D, Wroot + (size_t)l * D * D, Xout, N);
      Xin = Xout;
    }
  }
}

// Round 4
// 404.605 us; speedup vs baseline: 1.8729x; 1.8729x over previous
//
#include <hip/hip_runtime.h>

#define D 128
#define LDR 264  // LDS row stride in bf16 units (128+128 + 8 pad -> conflict-free b128)

typedef short bf16x8 __attribute__((ext_vector_type(8)));
typedef float f32x4 __attribute__((ext_vector_type(4)));

__device__ __forceinline__ unsigned short f2bf(float f) {
  unsigned int u = __float_as_uint(f);
  unsigned int r = (u + 0x7fff + ((u >> 16) & 1)) >> 16;
  return (unsigned short)r;
}
__device__ __forceinline__ float bf2f(unsigned short h) {
  return __uint_as_float((unsigned int)h << 16);
}

// ---------------- CSR build ----------------

__global__ void k_count(const int* __restrict__ dst, int* __restrict__ deg, int E) {
  int e = blockIdx.x * blockDim.x + threadIdx.x;
  if (e < E) atomicAdd(&deg[dst[e]], 1);
}

__global__ void k_scan_intra(const int* __restrict__ deg, int* __restrict__ row_off,
                             int* __restrict__ partials, int N) {
  __shared__ int s[256];
  int t = threadIdx.x;
  int i = blockIdx.x * 256 + t;
  int v = (i < N) ? deg[i] : 0;
  s[t] = v;
  __syncthreads();
  for (int off = 1; off < 256; off <<= 1) {
    int x = 0;
    if (t >= off) x = s[t - off];
    __syncthreads();
    if (t >= off) s[t] += x;
    __syncthreads();
  }
  if (i < N) row_off[i] = s[t] - v;
  if (t == 255) partials[blockIdx.x] = s[255];
}

__global__ void k_scan_partials(int* partials, int NB) {
  __shared__ int s[256];
  __shared__ int carry;
  int t = threadIdx.x;
  if (t == 0) carry = 0;
  __syncthreads();
  for (int base = 0; base < NB; base += 256) {
    int i = base + t;
    int v = (i < NB) ? partials[i] : 0;
    s[t] = v;
    __syncthreads();
    for (int off = 1; off < 256; off <<= 1) {
      int x = 0;
      if (t >= off) x = s[t - off];
      __syncthreads();
      if (t >= off) s[t] += x;
      __syncthreads();
    }
    if (i < NB) partials[i] = carry + s[t] - v;
    __syncthreads();
    if (t == 255) carry += s[255];
    __syncthreads();
  }
}

__global__ void k_finalize(int* __restrict__ row_off, const int* __restrict__ partials,
                           const int* __restrict__ deg, float* __restrict__ inv_deg,
                           int N, int E) {
  int i = blockIdx.x * 256 + threadIdx.x;
  if (i < N) {
    row_off[i] += partials[blockIdx.x];
    inv_deg[i] = 1.0f / fmaxf((float)deg[i], 1.0f);
  }
  if (i == N) row_off[N] = E;
}

__global__ void k_fill(const int* __restrict__ src, const int* __restrict__ dst,
                       const int* __restrict__ row_off, int* __restrict__ cursor,
                       int* __restrict__ csr, int E) {
  int e = blockIdx.x * blockDim.x + threadIdx.x;
  if (e < E) {
    int d = dst[e];
    int p = atomicAdd(&cursor[d], 1);
    csr[row_off[d] + p] = src[e];
  }
}

// ---------------- bf16 prep ----------------

__global__ void k_convert_x(const float* __restrict__ X0, unsigned short* __restrict__ Xb,
                            int total4) {
  int i = blockIdx.x * blockDim.x + threadIdx.x;
  if (i < total4) {
    float4 v = ((const float4*)X0)[i];
    ushort4 o;
    o.x = f2bf(v.x); o.y = f2bf(v.y); o.z = f2bf(v.z); o.w = f2bf(v.w);
    ((ushort4*)Xb)[i] = o;
  }
}

// Pre-swizzle W into MFMA B-operand lane layout.
// Wp[l][ks][ctg][lane][j] = Wcomb[ks*32 + (lane>>4)*8 + j][ctg*16 + (lane&15)]
// where Wcomb = [Wrel_l ; Wroot_l] (256 x 128).
__global__ void k_wprep(const float* __restrict__ Wrel, const float* __restrict__ Wroot,
                        unsigned short* __restrict__ Wp, int total) {
  int gid = blockIdx.x * blockDim.x + threadIdx.x;
  if (gid >= total) return;
  int lane = gid & 63;
  int t = gid >> 6;
  int ctg = t & 7; t >>= 3;
  int ks = t & 7; t >>= 3;
  int l = t;
  const float* Wr = Wrel + (size_t)l * D * D;
  const float* Wo = Wroot + (size_t)l * D * D;
  int colc = ctg * 16 + (lane & 15);
  int krow0 = ks * 32 + (lane >> 4) * 8;
  unsigned short tmp[8];
#pragma unroll
  for (int j = 0; j < 8; ++j) {
    int kr = krow0 + j;
    float w = (kr < D) ? Wr[(size_t)kr * D + colc] : Wo[(size_t)(kr - D) * D + colc];
    tmp[j] = f2bf(w);
  }
  unsigned short* dstp = Wp + ((size_t)gid) * 8;
#pragma unroll
  for (int j = 0; j < 8; ++j) dstp[j] = tmp[j];
}

// ---------------- per-layer kernels ----------------

// One wave per node; lane covers 2 bf16 features (4B/lane -> 256B/row coalesced).
// fp32 accumulate, bf16 out.
__global__ __launch_bounds__(256) void k_aggregate(const unsigned short* __restrict__ X,
    const int* __restrict__ row_off, const int* __restrict__ csr,
    const float* __restrict__ inv_deg, unsigned short* __restrict__ agg, int N) {
  int wave = (int)((blockIdx.x * blockDim.x + threadIdx.x) >> 6);
  int lane = threadIdx.x & 63;
  if (wave >= N) return;
  int start = row_off[wave], end = row_off[wave + 1];
  float ax = 0.f, ay = 0.f;
  for (int base = start; base < end; base += 64) {
    int n = min(64, end - base);
    int eid = (lane < n) ? csr[base + lane] : 0;
    for (int j = 0; j < n; ++j) {
      int s = __shfl(eid, j);
      unsigned int v = *(const unsigned int*)(X + (size_t)s * D + 2 * lane);
      ax += __uint_as_float(v << 16);
      ay += __uint_as_float(v & 0xffff0000u);
    }
  }
  float inv = inv_deg[wave];
  unsigned int o = ((unsigned int)f2bf(ax * inv)) | (((unsigned int)f2bf(ay * inv)) << 16);
  *(unsigned int*)(agg + (size_t)wave * D + 2 * lane) = o;
}

// Fused bf16-MFMA layer: out = ELU([agg|X] @ [Wrel;Wroot] + b).
// 32-row tile, 4 waves: wave = (rowgroup 0/16) x (colhalf 0/64).
// A (K=256 per row) staged in LDS with +8 pad; B read pre-swizzled from global (L2).
// In-place safe for Xout==Xin: each block stages its rows before the barrier and
// writes only those rows.
__global__ __launch_bounds__(256) void k_layer(const unsigned short* agg,
    const unsigned short* Xin, const unsigned short* __restrict__ Wp_l,
    const float* __restrict__ bias, unsigned short* Xout, float* out_f32,
    int last, int N) {
  __shared__ __align__(16) unsigned short sRow[32 * LDR];
  int tid = threadIdx.x;
  int r0 = blockIdx.x * 32;

  for (int i = tid; i < 32 * 32; i += 256) {
    int r = i >> 5, ch = i & 31;
    int row = r0 + r;
    uint4 v = make_uint4(0, 0, 0, 0);
    if (row < N) {
      const unsigned short* srcp = (ch < 16)
          ? (agg + (size_t)row * D + ch * 8)
          : (Xin + (size_t)row * D + (ch - 16) * 8);
      v = *(const uint4*)srcp;
    }
    *(uint4*)(&sRow[r * LDR + ch * 8]) = v;
  }
  __syncthreads();

  int wave = tid >> 6, lane = tid & 63;
  int rg = (wave >> 1) * 16;    // row offset within tile
  int ch0 = (wave & 1) * 64;    // col offset
  int m = lane & 15, q = lane >> 4;

  f32x4 acc[4];
#pragma unroll
  for (int ct = 0; ct < 4; ++ct) acc[ct] = (f32x4){0.f, 0.f, 0.f, 0.f};

  const unsigned short* arow = &sRow[(rg + m) * LDR + q * 8];
  int ctbase = ch0 >> 4;
#pragma unroll
  for (int ks = 0; ks < 8; ++ks) {
    bf16x8 a = *(const bf16x8*)(arow + ks * 32);
#pragma unroll
    for (int ct = 0; ct < 4; ++ct) {
      const unsigned short* bp = Wp_l + ((size_t)((ks * 8 + ctbase + ct) * 64 + lane)) * 8;
      bf16x8 b = *(const bf16x8*)bp;
      acc[ct] = __builtin_amdgcn_mfma_f32_16x16x32_bf16(a, b, acc[ct], 0, 0, 0);
    }
  }

#pragma unroll
  for (int ct = 0; ct < 4; ++ct) {
    int col = ch0 + ct * 16 + m;
    float bv = bias[col];
    int rbase = r0 + rg + q * 4;
#pragma unroll
    for (int j = 0; j < 4; ++j) {
      int row = rbase + j;
      if (row < N) {
        float v = acc[ct][j] + bv;
        v = v > 0.f ? v : expm1f(v);
        if (last) out_f32[(size_t)row * D + col] = v;
        else Xout[(size_t)row * D + col] = f2bf(v);
      }
    }
  }
}

// ---------------- launch ----------------

extern "C" void kernel_launch(void* const* d_in, const int* in_sizes, int n_in,
                              void* d_out, int out_size, void* d_ws, size_t ws_size,
                              hipStream_t stream) {
  const float* X0    = (const float*)d_in[0];
  const int*   eidx  = (const int*)d_in[1];
  const float* Wrel  = (const float*)d_in[2];
  const float* brel  = (const float*)d_in[3];
  const float* Wroot = (const float*)d_in[4];
  float* out = (float*)d_out;

  const int N = in_sizes[0] / D;
  const int E = in_sizes[1] / 2;
  const int L = in_sizes[3] / D;
  const int* src = eidx;      // edge_index[0]
  const int* dst = eidx + E;  // edge_index[1]

  char* ws = (char*)d_ws;
  size_t off = 0;
  auto carve = [&](size_t bytes) -> void* {
    void* p = ws + off;
    off = (off + bytes + 255) & ~(size_t)255;
    return p;
  };
  unsigned short* Xb   = (unsigned short*)carve((size_t)N * D * sizeof(unsigned short));
  unsigned short* aggb = (unsigned short*)carve((size_t)N * D * sizeof(unsigned short));
  unsigned short* Wp   = (unsigned short*)carve((size_t)L * 4096 * 8 * sizeof(unsigned short));
  int*   deg     = (int*)carve((size_t)N * sizeof(int));
  int*   row_off = (int*)carve((size_t)(N + 1) * sizeof(int));
  int*   cursor  = (int*)carve((size_t)N * sizeof(int));
  int*   csr     = (int*)carve((size_t)E * sizeof(int));
  float* inv_deg = (float*)carve((size_t)N * sizeof(float));
  const int NB = (N + 255) / 256;
  int*   partials = (int*)carve((size_t)NB * sizeof(int));
  (void)ws_size; (void)n_in; (void)out_size;

  hipMemsetAsync(deg, 0, (size_t)N * sizeof(int), stream);
  hipMemsetAsync(cursor, 0, (size_t)N * sizeof(int), stream);

  const int eb = (E + 255) / 256;
  k_count<<<eb, 256, 0, stream>>>(dst, deg, E);
  k_scan_intra<<<NB, 256, 0, stream>>>(deg, row_off, partials, N);
  k_scan_partials<<<1, 256, 0, stream>>>(partials, NB);
  k_finalize<<<NB, 256, 0, stream>>>(row_off, partials, deg, inv_deg, N, E);
  k_fill<<<eb, 256, 0, stream>>>(src, dst, row_off, cursor, csr, E);

  const int total4 = N * D / 4;
  k_convert_x<<<(total4 + 255) / 256, 256, 0, stream>>>(X0, Xb, total4);
  const int wtot = L * 4096;
  k_wprep<<<(wtot + 255) / 256, 256, 0, stream>>>(Wrel, Wroot, Wp, wtot);

  const int ab = (N + 3) / 4;    // k_aggregate blocks (4 waves each)
  const int lb = (N + 31) / 32;  // k_layer blocks

  for (int l = 0; l < L; ++l) {
    k_aggregate<<<ab, 256, 0, stream>>>(Xb, row_off, csr, inv_deg, aggb, N);
    int last = (l == L - 1) ? 1 : 0;
    k_layer<<<lb, 256, 0, stream>>>(aggb, Xb, Wp + (size_t)l * 4096 * 8,
        brel + (size_t)l * D, Xb, out, last, N);
  }
}

// Round 5
// 326.993 us; speedup vs baseline: 2.3175x; 1.2374x over previous
//
#include <hip/hip_runtime.h>

#define D 128
#define LDR 264  // LDS row stride in bf16 units (128+128 + 8 pad -> conflict-free b128)

typedef short bf16x8 __attribute__((ext_vector_type(8)));
typedef float f32x4 __attribute__((ext_vector_type(4)));

__device__ __forceinline__ unsigned short f2bf(float f) {
  unsigned int u = __float_as_uint(f);
  unsigned int r = (u + 0x7fff + ((u >> 16) & 1)) >> 16;
  return (unsigned short)r;
}
__device__ __forceinline__ unsigned int pack2bf(float lo, float hi) {
  return (unsigned int)f2bf(lo) | ((unsigned int)f2bf(hi) << 16);
}

// ---------------- CSR build ----------------

__global__ void k_count(const int* __restrict__ dst, int* __restrict__ deg, int E) {
  int e = blockIdx.x * blockDim.x + threadIdx.x;
  if (e < E) atomicAdd(&deg[dst[e]], 1);
}

__global__ void k_scan_intra(const int* __restrict__ deg, int* __restrict__ row_off,
                             int* __restrict__ partials, int N) {
  __shared__ int s[256];
  int t = threadIdx.x;
  int i = blockIdx.x * 256 + t;
  int v = (i < N) ? deg[i] : 0;
  s[t] = v;
  __syncthreads();
  for (int off = 1; off < 256; off <<= 1) {
    int x = 0;
    if (t >= off) x = s[t - off];
    __syncthreads();
    if (t >= off) s[t] += x;
    __syncthreads();
  }
  if (i < N) row_off[i] = s[t] - v;
  if (t == 255) partials[blockIdx.x] = s[255];
}

__global__ void k_scan_partials(int* partials, int NB) {
  __shared__ int s[256];
  __shared__ int carry;
  int t = threadIdx.x;
  if (t == 0) carry = 0;
  __syncthreads();
  for (int base = 0; base < NB; base += 256) {
    int i = base + t;
    int v = (i < NB) ? partials[i] : 0;
    s[t] = v;
    __syncthreads();
    for (int off = 1; off < 256; off <<= 1) {
      int x = 0;
      if (t >= off) x = s[t - off];
      __syncthreads();
      if (t >= off) s[t] += x;
      __syncthreads();
    }
    if (i < NB) partials[i] = carry + s[t] - v;
    __syncthreads();
    if (t == 255) carry += s[255];
    __syncthreads();
  }
}

__global__ void k_finalize(int* __restrict__ row_off, const int* __restrict__ partials,
                           const int* __restrict__ deg, float* __restrict__ inv_deg,
                           int N, int E) {
  int i = blockIdx.x * 256 + threadIdx.x;
  if (i < N) {
    row_off[i] += partials[blockIdx.x];
    inv_deg[i] = 1.0f / fmaxf((float)deg[i], 1.0f);
  }
  if (i == N) row_off[N] = E;
}

__global__ void k_fill(const int* __restrict__ src, const int* __restrict__ dst,
                       const int* __restrict__ row_off, int* __restrict__ cursor,
                       int* __restrict__ csr, int E) {
  int e = blockIdx.x * blockDim.x + threadIdx.x;
  if (e < E) {
    int d = dst[e];
    int p = atomicAdd(&cursor[d], 1);
    csr[row_off[d] + p] = src[e];
  }
}

// ---------------- bf16 prep ----------------

__global__ void k_convert_x(const float* __restrict__ X0, unsigned short* __restrict__ Xb,
                            int total4) {
  int i = blockIdx.x * blockDim.x + threadIdx.x;
  if (i < total4) {
    float4 v = ((const float4*)X0)[i];
    ushort4 o;
    o.x = f2bf(v.x); o.y = f2bf(v.y); o.z = f2bf(v.z); o.w = f2bf(v.w);
    ((ushort4*)Xb)[i] = o;
  }
}

// Pre-swizzle W into MFMA B-operand lane layout.
// Wp[l][ks][ctg][lane][j] = Wcomb[ks*32 + (lane>>4)*8 + j][ctg*16 + (lane&15)]
// where Wcomb = [Wrel_l ; Wroot_l] (256 x 128).
__global__ void k_wprep(const float* __restrict__ Wrel, const float* __restrict__ Wroot,
                        unsigned short* __restrict__ Wp, int total) {
  int gid = blockIdx.x * blockDim.x + threadIdx.x;
  if (gid >= total) return;
  int lane = gid & 63;
  int t = gid >> 6;
  int ctg = t & 7; t >>= 3;
  int ks = t & 7; t >>= 3;
  int l = t;
  const float* Wr = Wrel + (size_t)l * D * D;
  const float* Wo = Wroot + (size_t)l * D * D;
  int colc = ctg * 16 + (lane & 15);
  int krow0 = ks * 32 + (lane >> 4) * 8;
  unsigned short tmp[8];
#pragma unroll
  for (int j = 0; j < 8; ++j) {
    int kr = krow0 + j;
    float w = (kr < D) ? Wr[(size_t)kr * D + colc] : Wo[(size_t)(kr - D) * D + colc];
    tmp[j] = f2bf(w);
  }
  unsigned short* dstp = Wp + ((size_t)gid) * 8;
#pragma unroll
  for (int j = 0; j < 8; ++j) dstp[j] = tmp[j];
}

// ---------------- per-layer kernels ----------------

// One wave per node; 4 lane-groups of 16 process 4 edges concurrently,
// each group reads one full 256B row (uint4/lane). Main loop keeps 8 edges
// (2 independent dwordx4 loads) in flight. fp32 accumulate, bf16 out.
__global__ __launch_bounds__(256) void k_aggregate(const unsigned short* __restrict__ X,
    const int* __restrict__ row_off, const int* __restrict__ csr,
    const float* __restrict__ inv_deg, unsigned short* __restrict__ agg, int N) {
  int wave = (int)((blockIdx.x * blockDim.x + threadIdx.x) >> 6);
  int lane = threadIdx.x & 63;
  if (wave >= N) return;
  int grp = lane >> 4;   // which edge of the quad
  int l16 = lane & 15;   // 16B chunk within the row
  int start = row_off[wave], end = row_off[wave + 1];

  float acc[8];
#pragma unroll
  for (int k = 0; k < 8; ++k) acc[k] = 0.f;

  for (int base = start; base < end; base += 64) {
    int n = min(64, end - base);
    int eid = (lane < n) ? csr[base + lane] : 0;
    int j4 = 0;
    for (; j4 + 8 <= n; j4 += 8) {
      int s0 = __shfl(eid, j4 + grp);
      int s1 = __shfl(eid, j4 + 4 + grp);
      uint4 v0 = *(const uint4*)(X + (size_t)s0 * D + l16 * 8);
      uint4 v1 = *(const uint4*)(X + (size_t)s1 * D + l16 * 8);
      acc[0] += __uint_as_float(v0.x << 16); acc[1] += __uint_as_float(v0.x & 0xffff0000u);
      acc[2] += __uint_as_float(v0.y << 16); acc[3] += __uint_as_float(v0.y & 0xffff0000u);
      acc[4] += __uint_as_float(v0.z << 16); acc[5] += __uint_as_float(v0.z & 0xffff0000u);
      acc[6] += __uint_as_float(v0.w << 16); acc[7] += __uint_as_float(v0.w & 0xffff0000u);
      acc[0] += __uint_as_float(v1.x << 16); acc[1] += __uint_as_float(v1.x & 0xffff0000u);
      acc[2] += __uint_as_float(v1.y << 16); acc[3] += __uint_as_float(v1.y & 0xffff0000u);
      acc[4] += __uint_as_float(v1.z << 16); acc[5] += __uint_as_float(v1.z & 0xffff0000u);
      acc[6] += __uint_as_float(v1.w << 16); acc[7] += __uint_as_float(v1.w & 0xffff0000u);
    }
    for (; j4 < n; j4 += 4) {
      int jj = j4 + grp;
      int s = __shfl(eid, jj);
      if (jj < n) {
        uint4 v = *(const uint4*)(X + (size_t)s * D + l16 * 8);
        acc[0] += __uint_as_float(v.x << 16); acc[1] += __uint_as_float(v.x & 0xffff0000u);
        acc[2] += __uint_as_float(v.y << 16); acc[3] += __uint_as_float(v.y & 0xffff0000u);
        acc[4] += __uint_as_float(v.z << 16); acc[5] += __uint_as_float(v.z & 0xffff0000u);
        acc[6] += __uint_as_float(v.w << 16); acc[7] += __uint_as_float(v.w & 0xffff0000u);
      }
    }
  }

  // combine the 4 groups (lane bits 4 and 5)
#pragma unroll
  for (int k = 0; k < 8; ++k) {
    acc[k] += __shfl_xor(acc[k], 16);
    acc[k] += __shfl_xor(acc[k], 32);
  }

  if (grp == 0) {
    float inv = inv_deg[wave];
    uint4 o;
    o.x = pack2bf(acc[0] * inv, acc[1] * inv);
    o.y = pack2bf(acc[2] * inv, acc[3] * inv);
    o.z = pack2bf(acc[4] * inv, acc[5] * inv);
    o.w = pack2bf(acc[6] * inv, acc[7] * inv);
    *(uint4*)(agg + (size_t)wave * D + l16 * 8) = o;
  }
}

// Fused bf16-MFMA layer: out = ELU([agg|X] @ [Wrel;Wroot] + b).
// 32-row tile, 4 waves: wave = (rowgroup 0/16) x (colhalf 0/64).
// A (K=256 per row) staged in LDS with +8 pad; B read pre-swizzled from global (L2).
// In-place safe for Xout==Xin: each block stages its rows before the barrier and
// writes only those rows.
__global__ __launch_bounds__(256) void k_layer(const unsigned short* agg,
    const unsigned short* Xin, const unsigned short* __restrict__ Wp_l,
    const float* __restrict__ bias, unsigned short* Xout, float* out_f32,
    int last, int N) {
  __shared__ __align__(16) unsigned short sRow[32 * LDR];
  int tid = threadIdx.x;
  int r0 = blockIdx.x * 32;

  for (int i = tid; i < 32 * 32; i += 256) {
    int r = i >> 5, ch = i & 31;
    int row = r0 + r;
    uint4 v = make_uint4(0, 0, 0, 0);
    if (row < N) {
      const unsigned short* srcp = (ch < 16)
          ? (agg + (size_t)row * D + ch * 8)
          : (Xin + (size_t)row * D + (ch - 16) * 8);
      v = *(const uint4*)srcp;
    }
    *(uint4*)(&sRow[r * LDR + ch * 8]) = v;
  }
  __syncthreads();

  int wave = tid >> 6, lane = tid & 63;
  int rg = (wave >> 1) * 16;    // row offset within tile
  int ch0 = (wave & 1) * 64;    // col offset
  int m = lane & 15, q = lane >> 4;

  f32x4 acc[4];
#pragma unroll
  for (int ct = 0; ct < 4; ++ct) acc[ct] = (f32x4){0.f, 0.f, 0.f, 0.f};

  const unsigned short* arow = &sRow[(rg + m) * LDR + q * 8];
  int ctbase = ch0 >> 4;
#pragma unroll
  for (int ks = 0; ks < 8; ++ks) {
    bf16x8 a = *(const bf16x8*)(arow + ks * 32);
#pragma unroll
    for (int ct = 0; ct < 4; ++ct) {
      const unsigned short* bp = Wp_l + ((size_t)((ks * 8 + ctbase + ct) * 64 + lane)) * 8;
      bf16x8 b = *(const bf16x8*)bp;
      acc[ct] = __builtin_amdgcn_mfma_f32_16x16x32_bf16(a, b, acc[ct], 0, 0, 0);
    }
  }

#pragma unroll
  for (int ct = 0; ct < 4; ++ct) {
    int col = ch0 + ct * 16 + m;
    float bv = bias[col];
    int rbase = r0 + rg + q * 4;
#pragma unroll
    for (int j = 0; j < 4; ++j) {
      int row = rbase + j;
      if (row < N) {
        float v = acc[ct][j] + bv;
        v = v > 0.f ? v : expm1f(v);
        if (last) out_f32[(size_t)row * D + col] = v;
        else Xout[(size_t)row * D + col] = f2bf(v);
      }
    }
  }
}

// ---------------- launch ----------------

extern "C" void kernel_launch(void* const* d_in, const int* in_sizes, int n_in,
                              void* d_out, int out_size, void* d_ws, size_t ws_size,
                              hipStream_t stream) {
  const float* X0    = (const float*)d_in[0];
  const int*   eidx  = (const int*)d_in[1];
  const float* Wrel  = (const float*)d_in[2];
  const float* brel  = (const float*)d_in[3];
  const float* Wroot = (const float*)d_in[4];
  float* out = (float*)d_out;

  const int N = in_sizes[0] / D;
  const int E = in_sizes[1] / 2;
  const int L = in_sizes[3] / D;
  const int* src = eidx;      // edge_index[0]
  const int* dst = eidx + E;  // edge_index[1]

  char* ws = (char*)d_ws;
  size_t off = 0;
  auto carve = [&](size_t bytes) -> void* {
    void* p = ws + off;
    off = (off + bytes + 255) & ~(size_t)255;
    return p;
  };
  unsigned short* Xb   = (unsigned short*)carve((size_t)N * D * sizeof(unsigned short));
  unsigned short* aggb = (unsigned short*)carve((size_t)N * D * sizeof(unsigned short));
  unsigned short* Wp   = (unsigned short*)carve((size_t)L * 4096 * 8 * sizeof(unsigned short));
  int*   deg     = (int*)carve((size_t)N * sizeof(int));
  int*   row_off = (int*)carve((size_t)(N + 1) * sizeof(int));
  int*   cursor  = (int*)carve((size_t)N * sizeof(int));
  int*   csr     = (int*)carve((size_t)E * sizeof(int));
  float* inv_deg = (float*)carve((size_t)N * sizeof(float));
  const int NB = (N + 255) / 256;
  int*   partials = (int*)carve((size_t)NB * sizeof(int));
  (void)ws_size; (void)n_in; (void)out_size;

  hipMemsetAsync(deg, 0, (size_t)N * sizeof(int), stream);
  hipMemsetAsync(cursor, 0, (size_t)N * sizeof(int), stream);

  const int eb = (E + 255) / 256;
  k_count<<<eb, 256, 0, stream>>>(dst, deg, E);
  k_scan_intra<<<NB, 256, 0, stream>>>(deg, row_off, partials, N);
  k_scan_partials<<<1, 256, 0, stream>>>(partials, NB);
  k_finalize<<<NB, 256, 0, stream>>>(row_off, partials, deg, inv_deg, N, E);
  k_fill<<<eb, 256, 0, stream>>>(src, dst, row_off, cursor, csr, E);

  const int total4 = N * D / 4;
  k_convert_x<<<(total4 + 255) / 256, 256, 0, stream>>>(X0, Xb, total4);
  const int wtot = L * 4096;
  k_wprep<<<(wtot + 255) / 256, 256, 0, stream>>>(Wrel, Wroot, Wp, wtot);

  const int ab = (N + 3) / 4;    // k_aggregate blocks (4 waves each)
  const int lb = (N + 31) / 32;  // k_layer blocks

  for (int l = 0; l < L; ++l) {
    k_aggregate<<<ab, 256, 0, stream>>>(Xb, row_off, csr, inv_deg, aggb, N);
    int last = (l == L - 1) ? 1 : 0;
    k_layer<<<lb, 256, 0, stream>>>(aggb, Xb, Wp + (size_t)l * 4096 * 8,
        brel + (size_t)l * D, Xb, out, last, N);
  }
}